// Round 2
// baseline (1266.978 us; speedup 1.0000x reference)
//
#include <hip/hip_runtime.h>
#include <stdint.h>

#define NCLS 80
#define MAXB 150
#define BATCH 16
#define NANCH 25200
#define CAP 4096
#define CAP2 12000   // hard bound: 80 classes * 150 kept max

typedef unsigned long long u64;
typedef unsigned int u32;

__device__ __forceinline__ float sigm(float x) { return 1.0f / (1.0f + expf(-x)); }

// ---------------- Pass 1: coalesced decode + candidate compaction ----------------
// Each block stages RPT contiguous 85-float anchor records into LDS with float4
// loads (fully coalesced), then 1 thread/record computes from LDS.
#define RPT 128
#define TILE_F (RPT * 85)    // 10880 floats = 43520 B LDS
#define TILE_V (TILE_F / 4)  // 2720 float4 loads per tile

__global__ __launch_bounds__(256) void decode_kernel(
    const float* __restrict__ fm, int g, float ratio,
    float a0w, float a0h, float a1w, float a1h, float a2w, float a2h,
    int nbase, float* __restrict__ boxes_ws,
    u64* __restrict__ cand_keys, int* __restrict__ cand_cnt) {
  __shared__ float s[TILE_F];
  int tile = blockIdx.x, tid = threadIdx.x;
  const float4* src = reinterpret_cast<const float4*>(fm) + (size_t)tile * TILE_V;
  float4* sv = reinterpret_cast<float4*>(s);
  for (int i = tid; i < TILE_V; i += 256) sv[i] = src[i];
  __syncthreads();
  if (tid < RPT) {
    int gr = tile * RPT + tid;       // global record index within this level
    int gg3 = g * g * 3;
    int b = gr / gg3;
    int r = gr - b * gg3;
    int cell = r / 3, a = r - cell * 3;
    int y = cell / g, x = cell - y * g;
    const float* p = s + tid * 85;   // stride 85 floats: gcd(85,32)=1 -> conflict-free
    float cx = (sigm(p[0]) + (float)x) * ratio;
    float cy = (sigm(p[1]) + (float)y) * ratio;
    float aw = (a == 0) ? a0w : ((a == 1) ? a1w : a2w);
    float ah = (a == 0) ? a0h : ((a == 1) ? a1h : a2h);
    float w = expf(p[2]) * aw;
    float hh = expf(p[3]) * ah;
    int n = nbase + cell * 3 + a;
    float4 bx = make_float4(cx - w * 0.5f, cy - hh * 0.5f,
                            cx + w * 0.5f, cy + hh * 0.5f);
    reinterpret_cast<float4*>(boxes_ws)[(size_t)b * NANCH + n] = bx;
    float cs = sigm(p[4]);
    // score = cs*ps <= cs in fp32 -> cs > 0.9 is an exact-safe necessary condition
    if (cs > 0.9f) {
      for (int c = 0; c < NCLS; ++c) {
        float pl = p[5 + c];
        if (pl > 2.19f) {  // sigm(2.19)=0.8994 < 0.9/cs for any cs<=1 -> lossless pre-cull
          float sc = cs * sigm(pl);
          if (sc > 0.9f) {
            int bc = b * NCLS + c;
            int pos = atomicAdd(&cand_cnt[bc], 1);
            if (pos < CAP) {
              // high = score bits (positive float -> monotone), low = ~anchor idx
              // descending sort => score desc, lowest anchor idx first on ties
              cand_keys[(size_t)bc * CAP + pos] =
                  ((u64)__float_as_uint(sc) << 32) | (u32)(0xFFFFFFFFu - (u32)n);
            }
          }
        }
      }
    }
  }
}

// ---------------- Pass 2: per-(image,class) top-150 + greedy NMS ----------------
// Sorts only next_pow2(count) elements; appends kept entries to per-image list.
__global__ __launch_bounds__(256) void nms_kernel(
    const u64* __restrict__ cand_keys, const int* __restrict__ cand_cnt,
    const float* __restrict__ boxes_ws,
    u64* __restrict__ img_keys, int* __restrict__ img_cnt) {
  __shared__ u64 sk[CAP];
  __shared__ float4 sbox[MAXB];
  __shared__ float sarea[MAXB];
  __shared__ unsigned char svalid[MAXB];
  __shared__ unsigned char ssup[MAXB];
  int bc = blockIdx.x;
  int b = bc / NCLS, c = bc - b * NCLS;
  int tid = threadIdx.x;
  int count = cand_cnt[bc];
  if (count > CAP) count = CAP;
  int n = 256;
  while (n < count) n <<= 1;  // sort size: smallest pow2 >= count (>=256)
  const u64* src = cand_keys + (size_t)bc * CAP;
  for (int i = tid; i < n; i += 256) sk[i] = (i < count) ? src[i] : 0ull;
  __syncthreads();
  // bitonic sort, descending (zeros sink to the end)
  for (int k = 2; k <= n; k <<= 1) {
    for (int j = k >> 1; j > 0; j >>= 1) {
      for (int i = tid; i < n; i += 256) {
        int ixj = i ^ j;
        if (ixj > i) {
          u64 va = sk[i], vb = sk[ixj];
          if (((i & k) == 0) ? (va < vb) : (va > vb)) { sk[i] = vb; sk[ixj] = va; }
        }
      }
      __syncthreads();
    }
  }
  int myanchor = 0;
  if (tid < MAXB) {
    bool v = tid < count;
    float4 bx = make_float4(0.f, 0.f, 0.f, 0.f);
    if (v) {
      u64 key = sk[tid];
      myanchor = (int)(0xFFFFFFFFu - (u32)(key & 0xFFFFFFFFu));
      bx = reinterpret_cast<const float4*>(boxes_ws)[(size_t)b * NANCH + myanchor];
    }
    sbox[tid] = bx;
    sarea[tid] = (bx.z - bx.x) * (bx.w - bx.y);
    svalid[tid] = v ? 1 : 0;
    ssup[tid] = 0;
  }
  __syncthreads();
  float4 mybox = make_float4(0.f, 0.f, 0.f, 0.f);
  float myarea = 0.f;
  if (tid < MAXB) { mybox = sbox[tid]; myarea = sarea[tid]; }
  // greedy scan: sup[i] only set by iterations < i, so the order is exact.
  for (int i = 0; i < MAXB - 1; ++i) {
    if (svalid[i] && !ssup[i]) {
      if (tid > i && tid < MAXB) {
        float ltx = fmaxf(sbox[i].x, mybox.x);
        float lty = fmaxf(sbox[i].y, mybox.y);
        float rbx = fminf(sbox[i].z, mybox.z);
        float rby = fminf(sbox[i].w, mybox.w);
        float iw = fmaxf(rbx - ltx, 0.f);
        float ih = fmaxf(rby - lty, 0.f);
        float inter = iw * ih;
        float iou = inter / (sarea[i] + myarea - inter + 1e-9f);  // ref op order
        if (iou > 0.1f) ssup[tid] = 1;
      }
    }
    __syncthreads();
  }
  // append kept entries to the per-image list:
  // key = [score:32][(0x3FFF - e):14][anchor:15], e = c*150 + rank (tie: lower e wins)
  if (tid < MAXB && svalid[tid] && !ssup[tid]) {
    u32 sbits = (u32)(sk[tid] >> 32);
    u32 e = (u32)(c * MAXB + tid);
    int pos = atomicAdd(&img_cnt[b], 1);  // pos < 12000 guaranteed
    img_keys[(size_t)b * CAP2 + pos] =
        ((u64)sbits << 32) | ((u64)(0x3FFFu - e) << 15) | (u32)myanchor;
  }
}

// ---------------- Pass 3: per-image top-150 over kept entries ----------------
__global__ __launch_bounds__(1024) void final_kernel(
    const u64* __restrict__ img_keys, const int* __restrict__ img_cnt,
    const float* __restrict__ boxes_ws, float* __restrict__ out) {
  __shared__ u64 keys[CAP2];  // 96 KB
  __shared__ u64 wmax[16];
  __shared__ u64 swin;
  int b = blockIdx.x, tid = threadIdx.x;
  int L = img_cnt[b];
  if (L > CAP2) L = CAP2;
  for (int i = tid; i < L; i += 1024) keys[i] = img_keys[(size_t)b * CAP2 + i];
  __syncthreads();
  float* ob = out;                      // [B][150][4]
  float* osc = out + BATCH * MAXB * 4;  // [B][150]
  float* olb = out + BATCH * MAXB * 5;  // [B][150] labels as float
  for (int r = 0; r < MAXB; ++r) {
    u64 lm = 0;
    int lpos = -1;
    for (int i = tid; i < L; i += 1024) {
      u64 kk = keys[i];
      if (kk > lm) { lm = kk; lpos = i; }
    }
    u64 m = lm;
    for (int off = 32; off > 0; off >>= 1) {
      u64 o = __shfl_xor(m, off);
      if (o > m) m = o;
    }
    if ((tid & 63) == 0) wmax[tid >> 6] = m;
    __syncthreads();
    if (tid == 0) {
      u64 wbest = wmax[0];
      for (int i = 1; i < 16; ++i) if (wmax[i] > wbest) wbest = wmax[i];
      swin = wbest;
    }
    __syncthreads();
    u64 w = swin;
    if (w == 0) {  // no entries left -> -1 row
      if (tid == 0) {
        float* q = ob + ((size_t)b * MAXB + r) * 4;
        q[0] = q[1] = q[2] = q[3] = -1.f;
        osc[(size_t)b * MAXB + r] = -1.f;
        olb[(size_t)b * MAXB + r] = -1.f;
      }
    } else if (lm == w && lpos >= 0) {  // unique owner (keys unique)
      keys[lpos] = 0;
      u32 e = 0x3FFFu - (u32)((w >> 15) & 0x3FFFu);
      int c = e / MAXB;
      int anchor = (int)(w & 0x7FFFu);
      float4 bx = reinterpret_cast<const float4*>(boxes_ws)[(size_t)b * NANCH + anchor];
      float* q = ob + ((size_t)b * MAXB + r) * 4;
      q[0] = bx.x; q[1] = bx.y; q[2] = bx.z; q[3] = bx.w;
      osc[(size_t)b * MAXB + r] = __uint_as_float((u32)(w >> 32));
      olb[(size_t)b * MAXB + r] = (float)c;
    }
    __syncthreads();  // winner-clear visible before next round
  }
}

extern "C" void kernel_launch(void* const* d_in, const int* in_sizes, int n_in,
                              void* d_out, int out_size, void* d_ws, size_t ws_size,
                              hipStream_t stream) {
  (void)in_sizes; (void)n_in; (void)out_size; (void)ws_size;
  const float* p0 = (const float*)d_in[0];  // [16,20,20,255]
  const float* p1 = (const float*)d_in[1];  // [16,40,40,255]
  const float* p2 = (const float*)d_in[2];  // [16,80,80,255]
  char* ws = (char*)d_ws;
  // ws layout (bytes):
  float* boxes_ws = (float*)ws;              // 16*25200*16 B          -> 6,451,200
  int* cand_cnt = (int*)(ws + 6451200);      // 1280 i32               -> 6,456,320
  int* img_cnt = (int*)(ws + 6456320);       // 16 i32                 -> 6,456,384
  u64* cand_keys = (u64*)(ws + 6456384);     // 1280*4096 u64          -> 48,399,424
  u64* img_keys = (u64*)(ws + 48399424);     // 16*12000 u64           -> 49,935,424

  hipMemsetAsync(cand_cnt, 0, (NCLS * BATCH + BATCH) * sizeof(int), stream);

  // level order matches reference concat: p0 (anchors[6:9]), p1 (anchors[3:6]), p2 (anchors[0:3])
  int r0 = BATCH * 20 * 20 * 3;  // 19200 records (150 tiles)
  decode_kernel<<<r0 / RPT, 256, 0, stream>>>(
      p0, 20, 32.f, 116.f, 90.f, 156.f, 198.f, 373.f, 326.f, 0,
      boxes_ws, cand_keys, cand_cnt);
  int r1 = BATCH * 40 * 40 * 3;  // 76800 records (600 tiles)
  decode_kernel<<<r1 / RPT, 256, 0, stream>>>(
      p1, 40, 16.f, 30.f, 61.f, 62.f, 45.f, 59.f, 119.f, 1200,
      boxes_ws, cand_keys, cand_cnt);
  int r2 = BATCH * 80 * 80 * 3;  // 307200 records (2400 tiles)
  decode_kernel<<<r2 / RPT, 256, 0, stream>>>(
      p2, 80, 8.f, 10.f, 13.f, 16.f, 30.f, 33.f, 23.f, 6000,
      boxes_ws, cand_keys, cand_cnt);

  nms_kernel<<<BATCH * NCLS, 256, 0, stream>>>(cand_keys, cand_cnt, boxes_ws,
                                               img_keys, img_cnt);
  final_kernel<<<BATCH, 1024, 0, stream>>>(img_keys, img_cnt, boxes_ws, (float*)d_out);
}